// Round 1
// baseline (5055.844 us; speedup 1.0000x reference)
//
#include <hip/hip_runtime.h>
#include <stdint.h>

typedef _Float16 half_t;
typedef _Float16 half8 __attribute__((ext_vector_type(8)));
typedef float floatx4 __attribute__((ext_vector_type(4)));

#define D_MODEL 1024
#define NHEAD 8
#define DHEAD 128
#define FF_DIM 2048
#define NLAYER 3
#define BATCH 8
#define TSEQ 256
#define USEQ 1024
#define TPAD 128256
#define UPAD 10000
#define TEMP_ 5e-4f
#define SCALE_QK 0.08838834764831845f

// ---------------- block reduction helpers (block = 256 = 4 waves) ----------------
__device__ inline float blk_sum(float v, float* sh) {
#pragma unroll
  for (int o = 32; o; o >>= 1) v += __shfl_xor(v, o, 64);
  __syncthreads();
  if ((threadIdx.x & 63) == 0) sh[threadIdx.x >> 6] = v;
  __syncthreads();
  return sh[0] + sh[1] + sh[2] + sh[3];
}
__device__ inline float blk_max(float v, float* sh) {
#pragma unroll
  for (int o = 32; o; o >>= 1) v = fmaxf(v, __shfl_xor(v, o, 64));
  __syncthreads();
  if ((threadIdx.x & 63) == 0) sh[threadIdx.x >> 6] = v;
  __syncthreads();
  return fmaxf(fmaxf(sh[0], sh[1]), fmaxf(sh[2], sh[3]));
}

// ---------------- generic batched GEMM: C = alpha * A[M,K] * B[N,K]^T + bias ----------------
// 128x128 tile, 2-phase; used for small/odd shapes (PV with N=128, text encoder, cross).
__global__ __launch_bounds__(256)
void gemm_bt_kernel(const half_t* __restrict__ A, long lda, long sAb, long sAz,
                    const half_t* __restrict__ B, long ldb, long sBb, long sBz,
                    float* __restrict__ Cf, half_t* __restrict__ Ch,
                    long ldc, long sCb, long sCz,
                    const float* __restrict__ bias,
                    int M, int N, int K, float alpha, int relu, int zdiv) {
  __shared__ __align__(16) half_t As[128 * 64];
  __shared__ __align__(16) half_t Bs[128 * 64];

  const int z = blockIdx.z;
  const int zb = z / zdiv, zh = z % zdiv;
  A += (long)zb * sAb + (long)zh * sAz;
  B += (long)zb * sBb + (long)zh * sBz;
  const long coff = (long)zb * sCb + (long)zh * sCz;

  const int tid = threadIdx.x;
  const int lane = tid & 63;
  const int wid = tid >> 6;
  const long row0 = (long)blockIdx.y * 128;
  const long col0 = (long)blockIdx.x * 128;

  const int srow = tid >> 3;  // 0..31 staging row
  const int sg = tid & 7;     // staging granule (8 halves)

  const int wm = (wid & 1) << 6;
  const int wn = (wid >> 1) << 6;
  const int fm = lane & 15;
  const int quad = lane >> 4;

  floatx4 acc[4][4] = {};

  for (int k0 = 0; k0 < K; k0 += 64) {
#pragma unroll
    for (int i = 0; i < 4; ++i) {
      const int r = srow + (i << 5);
      const int gsw = (sg ^ (r & 7)) << 3;
      uint4 va = *(const uint4*)(A + (row0 + r) * lda + k0 + (sg << 3));
      *(uint4*)(&As[(r << 6) + gsw]) = va;
      uint4 vb = *(const uint4*)(B + (col0 + r) * ldb + k0 + (sg << 3));
      *(uint4*)(&Bs[(r << 6) + gsw]) = vb;
    }
    __syncthreads();
#pragma unroll
    for (int kk = 0; kk < 64; kk += 32) {
      const int gq = (kk >> 3) + quad;  // granule for this quad
      half8 af[4], bfr[4];
#pragma unroll
      for (int mi = 0; mi < 4; ++mi) {
        const int r = wm + (mi << 4) + fm;
        af[mi] = *(const half8*)(&As[(r << 6) + ((gq ^ (r & 7)) << 3)]);
      }
#pragma unroll
      for (int ni = 0; ni < 4; ++ni) {
        const int r = wn + (ni << 4) + fm;
        bfr[ni] = *(const half8*)(&Bs[(r << 6) + ((gq ^ (r & 7)) << 3)]);
      }
#pragma unroll
      for (int mi = 0; mi < 4; ++mi)
#pragma unroll
        for (int ni = 0; ni < 4; ++ni)
          acc[mi][ni] = __builtin_amdgcn_mfma_f32_16x16x32_f16(af[mi], bfr[ni], acc[mi][ni], 0, 0, 0);
    }
    __syncthreads();
  }

#pragma unroll
  for (int ni = 0; ni < 4; ++ni) {
    const long col = col0 + wn + (ni << 4) + fm;
    const float bv = bias ? bias[col] : 0.0f;
#pragma unroll
    for (int mi = 0; mi < 4; ++mi) {
#pragma unroll
      for (int r = 0; r < 4; ++r) {
        const long row = row0 + wm + (mi << 4) + (quad << 2) + r;
        float v = acc[mi][ni][r] * alpha + bv;
        if (relu) v = fmaxf(v, 0.0f);
        const long idx = coff + row * ldc + col;
        if (Cf) Cf[idx] = v;
        if (Ch) Ch[idx] = (half_t)v;
      }
    }
  }
}

// ---------------- 256x256 8-phase pipelined GEMM (big shapes) ----------------
// BM=BN=256, BK=64, 512 threads = 8 waves (2 row-strips x 4 col-strips).
// Per-wave output: rows {a*128 + wr*64 .. +64} x cols {b*128 + wc*32 .. +32}, a,b in {0,1}
// -> every wave reads the SAME (A-half, B-half) in a given phase, so staging the
// other buffer during compute is race-free with counted vmcnt (never drained to 0).
// Staging: global_load_lds width-16, linear LDS dest; source pre-swizzled so reads
// use granule XOR (g ^ (row&7)) -> conflict-free ds_read_b128 (rule both-sides-or-neither).
// Schedule per K-tile T (phases (a,b) = 00,01,10,11), staging tile T+1:
//   P1: issue A0,B0 ; wait vmcnt(6)  (confirms B1 of T)
//   P2: issue B1    ; wait vmcnt(6)  (confirms A1 of T)
//   P3: issue A1    ; no wait
//   P4: -           ; wait vmcnt(4)  (confirms A0,B0 of T+1)
// Last tile: waits 2,0,-,- (epilogue drain). Prologue: stage A0,B0,B1,A1; vmcnt(4).
typedef const __attribute__((address_space(1))) uint32_t* gas1_u32;
typedef __attribute__((address_space(3))) uint32_t* las3_u32;
__device__ __forceinline__ void gload16(const half_t* g, half_t* l) {
  __builtin_amdgcn_global_load_lds((gas1_u32)g, (las3_u32)l, 16, 0, 0);
}
#define VMW(n) asm volatile("s_waitcnt vmcnt(" #n ")" ::: "memory")

// stage one half-tile (128 rows x 64 halves) of src rows [roff, roff+128) cols [kc, kc+64)
// into dst (linear LDS region). 2 wave-level global_load_lds per wave.
#define STAGE(dst, src, ld, roff, kc)                                          \
  {                                                                            \
    _Pragma("unroll") for (int j_ = 0; j_ < 2; ++j_) {                         \
      const int rb_ = (j_ << 6) + (wid << 3);                                  \
      const int rr_ = rb_ + (lane >> 3);                                       \
      const int gg_ = (lane & 7) ^ (rr_ & 7);                                  \
      gload16((src) + ((long)(roff) + rr_) * (ld) + (kc) + (gg_ << 3),         \
              (dst) + (rb_ << 6));                                             \
    }                                                                          \
  }

#define PHASE(aa, bb, STG, WT)                                                 \
  {                                                                            \
    half8 af0_[4], af1_[4], bf0_[2], bf1_[2];                                  \
    _Pragma("unroll") for (int mi = 0; mi < 4; ++mi) {                         \
      const int r_ = (wr << 6) + (mi << 4) + fm;                               \
      half_t* ap_ = &As[d][aa][(r_ << 6)];                                     \
      af0_[mi] = *(const half8*)(ap_ + ((quad ^ (r_ & 7)) << 3));              \
      af1_[mi] = *(const half8*)(ap_ + (((4 + quad) ^ (r_ & 7)) << 3));        \
    }                                                                          \
    _Pragma("unroll") for (int ni = 0; ni < 2; ++ni) {                         \
      const int r_ = (wc << 5) + (ni << 4) + fm;                               \
      half_t* bp_ = &Bs[d][bb][(r_ << 6)];                                     \
      bf0_[ni] = *(const half8*)(bp_ + ((quad ^ (r_ & 7)) << 3));              \
      bf1_[ni] = *(const half8*)(bp_ + (((4 + quad) ^ (r_ & 7)) << 3));        \
    }                                                                          \
    STG;                                                                       \
    __builtin_amdgcn_s_barrier();                                              \
    __builtin_amdgcn_s_setprio(1);                                             \
    _Pragma("unroll") for (int mi = 0; mi < 4; ++mi)                           \
      _Pragma("unroll") for (int ni = 0; ni < 2; ++ni) {                       \
        acc[aa][bb][mi][ni] = __builtin_amdgcn_mfma_f32_16x16x32_f16(          \
            af0_[mi], bf0_[ni], acc[aa][bb][mi][ni], 0, 0, 0);                 \
        acc[aa][bb][mi][ni] = __builtin_amdgcn_mfma_f32_16x16x32_f16(          \
            af1_[mi], bf1_[ni], acc[aa][bb][mi][ni], 0, 0, 0);                 \
      }                                                                        \
    __builtin_amdgcn_s_setprio(0);                                             \
    WT;                                                                        \
    __builtin_amdgcn_s_barrier();                                              \
  }

__global__ __launch_bounds__(512, 2)
void gemm256_kernel(const half_t* __restrict__ A, long lda, long sAb, long sAz,
                    const half_t* __restrict__ B, long ldb, long sBb, long sBz,
                    float* __restrict__ Cf, half_t* __restrict__ Ch,
                    long ldc, long sCb, long sCz,
                    const float* __restrict__ bias,
                    int M, int N, int K, float alpha, int relu, int zdiv) {
  __shared__ __align__(16) half_t As[2][2][128 * 64];
  __shared__ __align__(16) half_t Bs[2][2][128 * 64];

  const int z = blockIdx.z;
  const int zb = z / zdiv, zh = z % zdiv;
  A += (long)zb * sAb + (long)zh * sAz;
  B += (long)zb * sBb + (long)zh * sBz;
  const long coff = (long)zb * sCb + (long)zh * sCz;

  // bijective XCD-aware swizzle of the (x,y) tile index (m204 variant)
  const int gx = (int)gridDim.x;
  const int nwg = gx * (int)gridDim.y;
  const int orig = (int)blockIdx.y * gx + (int)blockIdx.x;
  const int q_ = nwg >> 3, r_ = nwg & 7, x_ = orig & 7, i_ = orig >> 3;
  const int swz = (x_ < r_ ? x_ * (q_ + 1) : r_ * (q_ + 1) + (x_ - r_) * q_) + i_;
  const long row0 = (long)(swz / gx) * 256;
  const long col0 = (long)(swz % gx) * 256;

  const int tid = threadIdx.x;
  const int lane = tid & 63;
  const int wid = tid >> 6;   // 0..7
  const int wr = wid >> 2;    // row strip within each A-half
  const int wc = wid & 3;     // col strip within each B-half
  const int fm = lane & 15;
  const int quad = lane >> 4;

  floatx4 acc[2][2][4][2] = {};
  const int NT = K >> 6;

  // prologue: stage tile 0 (order A0, B0, B1, A1), confirm A0+B0
  STAGE(&As[0][0][0], A, lda, row0, 0);
  STAGE(&Bs[0][0][0], B, ldb, col0, 0);
  STAGE(&Bs[0][1][0], B, ldb, col0 + 128, 0);
  STAGE(&As[0][1][0], A, lda, row0 + 128, 0);
  VMW(4);
  __builtin_amdgcn_s_barrier();

  for (int t = 0; t < NT; ++t) {
    const int d = t & 1, e = d ^ 1;
    const int kn = (t + 1) << 6;
    if (t + 1 < NT) {
      PHASE(0, 0,
            { STAGE(&As[e][0][0], A, lda, row0, kn); STAGE(&Bs[e][0][0], B, ldb, col0, kn); },
            VMW(6));
      PHASE(0, 1, { STAGE(&Bs[e][1][0], B, ldb, col0 + 128, kn); }, VMW(6));
      PHASE(1, 0, { STAGE(&As[e][1][0], A, lda, row0 + 128, kn); }, ;);
      PHASE(1, 1, ;, VMW(4));
    } else {
      PHASE(0, 0, ;, VMW(2));
      PHASE(0, 1, ;, VMW(0));
      PHASE(1, 0, ;, ;);
      PHASE(1, 1, ;, ;);
    }
  }

  // epilogue: C/D layout col = lane&15, row = quad*4 + r
#pragma unroll
  for (int a2 = 0; a2 < 2; ++a2)
#pragma unroll
    for (int b2 = 0; b2 < 2; ++b2)
#pragma unroll
      for (int ni = 0; ni < 2; ++ni) {
        const long col = col0 + (b2 << 7) + (wc << 5) + (ni << 4) + fm;
        const float bv = bias ? bias[col] : 0.0f;
#pragma unroll
        for (int mi = 0; mi < 4; ++mi)
#pragma unroll
          for (int r = 0; r < 4; ++r) {
            const long row = row0 + (a2 << 7) + (wr << 6) + (mi << 4) + (quad << 2) + r;
            float v = acc[a2][b2][mi][ni][r] * alpha + bv;
            if (relu) v = fmaxf(v, 0.0f);
            const long idx = coff + row * ldc + col;
            if (Cf) Cf[idx] = v;
            if (Ch) Ch[idx] = (half_t)v;
          }
      }
}

// ---------------- elementwise / small kernels ----------------
__global__ void cvt_kernel(const float* __restrict__ in, half_t* __restrict__ out, long n) {
  long i = (long)blockIdx.x * 256 + threadIdx.x;
  const long stride = (long)gridDim.x * 256;
  for (; i < n; i += stride) out[i] = (half_t)in[i];
}

__global__ __launch_bounds__(256) void embed_kernel(const int* __restrict__ tok,
                                                    const float* __restrict__ emb,
                                                    float* __restrict__ xf, half_t* __restrict__ xh) {
  const long r = blockIdx.x;
  const long src = (long)tok[r] * D_MODEL;
  for (int j = threadIdx.x; j < D_MODEL; j += 256) {
    const float v = emb[src + j];
    xf[r * D_MODEL + j] = v;
    xh[r * D_MODEL + j] = (half_t)v;
  }
}

// x = LN(x + y) * s + b  (in-place on xf, also emits fp16 copy)
__global__ __launch_bounds__(256) void ln_kernel(float* x, const float* y,
                                                 const float* s, const float* b, half_t* xh) {
  const int row = blockIdx.x, tid = threadIdx.x;
  float* xr = x + (long)row * D_MODEL;
  const float* yr = y + (long)row * D_MODEL;
  float v[4], sum = 0.f, sq = 0.f;
#pragma unroll
  for (int c = 0; c < 4; ++c) {
    const int j = tid + (c << 8);
    const float t = xr[j] + yr[j];
    v[c] = t; sum += t; sq += t * t;
  }
  __shared__ float sh[4];
  sum = blk_sum(sum, sh);
  sq = blk_sum(sq, sh);
  const float mean = sum * (1.0f / D_MODEL);
  const float var = sq * (1.0f / D_MODEL) - mean * mean;
  const float inv = rsqrtf(var + 1e-5f);
#pragma unroll
  for (int c = 0; c < 4; ++c) {
    const int j = tid + (c << 8);
    const float t = (v[c] - mean) * inv * s[j] + b[j];
    xr[j] = t;
    xh[(long)row * D_MODEL + j] = (half_t)t;
  }
}

// in-place masked softmax over rows of sc[z][q][S]
__global__ __launch_bounds__(256) void softmax_kernel(half_t* sc, const int* __restrict__ tok,
                                                      int S, int padidx) {
  const int q = blockIdx.x, z = blockIdx.y;
  const int b = z >> 3;  // NHEAD == 8
  half_t* row = sc + (long)z * S * S + (long)q * S;
  const int* tb = tok + (long)b * S;
  const int nc = S >> 8;
  const int tid = threadIdx.x;
  float v[4];
  float m = -3e38f;
  for (int c = 0; c < nc; ++c) {
    const int j = tid + (c << 8);
    float x = (float)row[j];
    if (tb[j] == padidx) x = -1e9f;
    v[c] = x;
    m = fmaxf(m, x);
  }
  __shared__ float sh[4];
  m = blk_max(m, sh);
  float ssum = 0.f;
  for (int c = 0; c < nc; ++c) { v[c] = expf(v[c] - m); ssum += v[c]; }
  ssum = blk_sum(ssum, sh);
  const float inv = 1.0f / ssum;
  for (int c = 0; c < nc; ++c) row[tid + (c << 8)] = (half_t)(v[c] * inv);
}

// repack V section of qkv into vt[b*H+h][DHEAD][S] (transposed, for gemm_bt PV)
__global__ __launch_bounds__(256) void vtrans_kernel(const half_t* __restrict__ qkv,
                                                     half_t* __restrict__ vt, int S) {
  __shared__ half_t tile[64][65];
  const int s0 = blockIdx.x * 64, d0 = blockIdx.y * 64, z = blockIdx.z;
  const int b = z >> 3, h = z & 7;
  const half_t* src = qkv + (long)b * S * (3 * D_MODEL) + 2 * D_MODEL + h * DHEAD;
  for (int idx = threadIdx.x; idx < 4096; idx += 256) {
    const int r = idx >> 6, c = idx & 63;
    tile[r][c] = src[(long)(s0 + r) * (3 * D_MODEL) + d0 + c];
  }
  __syncthreads();
  half_t* dst = vt + ((long)z * DHEAD + d0) * S + s0;
  for (int idx = threadIdx.x; idx < 4096; idx += 256) {
    const int r = idx >> 6, c = idx & 63;
    dst[(long)r * S + c] = tile[c][r];
  }
}

__global__ __launch_bounds__(256) void rowsq_kernel(const float* __restrict__ x, float* __restrict__ o) {
  const int row = blockIdx.x, tid = threadIdx.x;
  const float* xr = x + (long)row * D_MODEL;
  float s = 0.f;
#pragma unroll
  for (int c = 0; c < 4; ++c) { const float t = xr[tid + (c << 8)]; s += t * t; }
  __shared__ float sh[4];
  s = blk_sum(s, sh);
  if (tid == 0) o[row] = s;
}

// out row currently holds cross[b,u,:]; transform to log_softmax(-TEMP*(un+tn-2c)) with pad mask
__global__ __launch_bounds__(256) void dist_lsm_kernel(float* out, const float* __restrict__ un,
                                                       const float* __restrict__ tn,
                                                       const int* __restrict__ utok,
                                                       const int* __restrict__ ttok) {
  const int u = blockIdx.x, b = blockIdx.y, t = threadIdx.x;
  const long off = ((long)(b * USEQ + u)) * TSEQ;
  const float c = out[off + t];
  float x = -TEMP_ * (un[b * USEQ + u] + tn[b * TSEQ + t] - 2.0f * c);
  if (utok[b * USEQ + u] == UPAD || ttok[b * TSEQ + t] == TPAD) x = -1e9f;
  __shared__ float sh[4];
  const float m = blk_max(x, sh);
  const float e = expf(x - m);
  const float s = blk_sum(e, sh);
  out[off + t] = x - m - logf(s);
}

// ---------------- host-side orchestration ----------------
static void launch_gemm(hipStream_t st, const half_t* A, long lda, long sAb, long sAz,
                        const half_t* B, long ldb, long sBb, long sBz,
                        float* Cf, half_t* Ch, long ldc, long sCb, long sCz,
                        const float* bias, int M, int N, int K, float alpha, int relu,
                        int zdiv, int nz) {
  const long nb256 = ((M & 255) || (N & 255)) ? 0 : (long)(M / 256) * (N / 256) * nz;
  if (nb256 >= 128) {
    dim3 g(N / 256, M / 256, nz), blk(512);
    gemm256_kernel<<<g, blk, 0, st>>>(A, lda, sAb, sAz, B, ldb, sBb, sBz,
                                      Cf, Ch, ldc, sCb, sCz, bias, M, N, K, alpha, relu, zdiv);
  } else {
    dim3 g(N / 128, M / 128, nz), blk(256);
    gemm_bt_kernel<<<g, blk, 0, st>>>(A, lda, sAb, sAz, B, ldb, sBb, sBz,
                                      Cf, Ch, ldc, sCb, sCz, bias, M, N, K, alpha, relu, zdiv);
  }
}

struct EncW {
  const int* tok; int S;
  const float *emb, *ipb, *ob, *l1s, *l1b, *f1b, *f2b, *l2s, *l2b;
  const half_t *ipw, *ow, *f1w, *f2w;
  int padidx;
};
struct Bufs {
  float *xf, *yf;
  half_t *xh, *qkv, *vt, *sc, *oh, *ffh;
};

static void run_encoder(hipStream_t st, const EncW& w, const Bufs& bb) {
  const int S = w.S, Ntok = BATCH * S;
  embed_kernel<<<Ntok, 256, 0, st>>>(w.tok, w.emb, bb.xf, bb.xh);
  for (int l = 0; l < NLAYER; ++l) {
    // QKV projection -> qkv[Ntok, 3D] fp16
    launch_gemm(st, bb.xh, D_MODEL, 0, 0,
                w.ipw + (size_t)l * 3 * D_MODEL * D_MODEL, D_MODEL, 0, 0,
                nullptr, bb.qkv, 3 * D_MODEL, 0, 0,
                w.ipb + (size_t)l * 3 * D_MODEL, Ntok, 3 * D_MODEL, D_MODEL, 1.0f, 0, 1, 1);
    // V transpose repack
    vtrans_kernel<<<dim3(S / 64, DHEAD / 64, BATCH * NHEAD), 256, 0, st>>>(bb.qkv, bb.vt, S);
    // scores = scale * Q K^T   (per z = b*H + h, strided into qkv)
    launch_gemm(st, bb.qkv, 3 * D_MODEL, (long)S * 3 * D_MODEL, DHEAD,
                bb.qkv + D_MODEL, 3 * D_MODEL, (long)S * 3 * D_MODEL, DHEAD,
                nullptr, bb.sc, S, (long)NHEAD * S * S, (long)S * S,
                nullptr, S, S, DHEAD, SCALE_QK, 0, NHEAD, BATCH * NHEAD);
    softmax_kernel<<<dim3(S, BATCH * NHEAD), 256, 0, st>>>(bb.sc, w.tok, S, w.padidx);
    // O_head = P V  -> oh[Ntok, D] (heads concatenated)
    launch_gemm(st, bb.sc, S, (long)NHEAD * S * S, (long)S * S,
                bb.vt, S, (long)NHEAD * DHEAD * S, (long)DHEAD * S,
                nullptr, bb.oh, D_MODEL, (long)S * D_MODEL, DHEAD,
                nullptr, S, DHEAD, S, 1.0f, 0, NHEAD, BATCH * NHEAD);
    // output projection -> yf fp32
    launch_gemm(st, bb.oh, D_MODEL, 0, 0,
                w.ow + (size_t)l * D_MODEL * D_MODEL, D_MODEL, 0, 0,
                bb.yf, nullptr, D_MODEL, 0, 0,
                w.ob + (size_t)l * D_MODEL, Ntok, D_MODEL, D_MODEL, 1.0f, 0, 1, 1);
    ln_kernel<<<Ntok, 256, 0, st>>>(bb.xf, bb.yf, w.l1s + (size_t)l * D_MODEL,
                                    w.l1b + (size_t)l * D_MODEL, bb.xh);
    // FF1 (+ReLU) -> ffh fp16
    launch_gemm(st, bb.xh, D_MODEL, 0, 0,
                w.f1w + (size_t)l * FF_DIM * D_MODEL, D_MODEL, 0, 0,
                nullptr, bb.ffh, FF_DIM, 0, 0,
                w.f1b + (size_t)l * FF_DIM, Ntok, FF_DIM, D_MODEL, 1.0f, 1, 1, 1);
    // FF2 -> yf fp32
    launch_gemm(st, bb.ffh, FF_DIM, 0, 0,
                w.f2w + (size_t)l * D_MODEL * FF_DIM, FF_DIM, 0, 0,
                bb.yf, nullptr, D_MODEL, 0, 0,
                w.f2b + (size_t)l * D_MODEL, Ntok, D_MODEL, FF_DIM, 1.0f, 0, 1, 1);
    ln_kernel<<<Ntok, 256, 0, st>>>(bb.xf, bb.yf, w.l2s + (size_t)l * D_MODEL,
                                    w.l2b + (size_t)l * D_MODEL, bb.xh);
  }
}

extern "C" void kernel_launch(void* const* d_in, const int* in_sizes, int n_in,
                              void* d_out, int out_size, void* d_ws, size_t ws_size,
                              hipStream_t stream) {
  (void)in_sizes; (void)n_in; (void)out_size; (void)ws_size;
  const int* ttok = (const int*)d_in[0];
  const int* utok = (const int*)d_in[1];
  const float* tp[13];
  const float* up[13];
  for (int i = 0; i < 13; ++i) tp[i] = (const float*)d_in[2 + i];
  for (int i = 0; i < 13; ++i) up[i] = (const float*)d_in[15 + i];
  // index: 0 emb, 1 ipw, 2 ipb, 3 ow, 4 ob, 5 l1s, 6 l1b, 7 f1w, 8 f1b, 9 f2w, 10 f2b, 11 l2s, 12 l2b

  char* wp = (char*)d_ws;
  auto alloc = [&](size_t bytes) {
    void* p = wp;
    wp += (bytes + 255) & ~(size_t)255;
    return p;
  };
  const size_t IPW = (size_t)NLAYER * 3 * D_MODEL * D_MODEL;
  const size_t OW = (size_t)NLAYER * D_MODEL * D_MODEL;
  const size_t F1W = (size_t)NLAYER * FF_DIM * D_MODEL;
  const size_t F2W = (size_t)NLAYER * D_MODEL * FF_DIM;
  half_t* t_ipw = (half_t*)alloc(IPW * 2);
  half_t* t_ow = (half_t*)alloc(OW * 2);
  half_t* t_f1w = (half_t*)alloc(F1W * 2);
  half_t* t_f2w = (half_t*)alloc(F2W * 2);
  half_t* u_ipw = (half_t*)alloc(IPW * 2);
  half_t* u_ow = (half_t*)alloc(OW * 2);
  half_t* u_f1w = (half_t*)alloc(F1W * 2);
  half_t* u_f2w = (half_t*)alloc(F2W * 2);
  Bufs bb;
  bb.xf = (float*)alloc((size_t)BATCH * USEQ * D_MODEL * 4);
  bb.yf = (float*)alloc((size_t)BATCH * USEQ * D_MODEL * 4);
  bb.xh = (half_t*)alloc((size_t)BATCH * USEQ * D_MODEL * 2);
  bb.qkv = (half_t*)alloc((size_t)BATCH * USEQ * 3 * D_MODEL * 2);
  bb.vt = (half_t*)alloc((size_t)BATCH * NHEAD * DHEAD * USEQ * 2);
  bb.sc = (half_t*)alloc((size_t)BATCH * NHEAD * USEQ * USEQ * 2);
  bb.oh = (half_t*)alloc((size_t)BATCH * USEQ * D_MODEL * 2);
  bb.ffh = (half_t*)alloc((size_t)BATCH * USEQ * FF_DIM * 2);
  half_t* tfh = (half_t*)alloc((size_t)BATCH * TSEQ * D_MODEL * 2);
  float* tn = (float*)alloc((size_t)BATCH * TSEQ * 4);
  float* un = (float*)alloc((size_t)BATCH * USEQ * 4);

  // weight fp32 -> fp16
  cvt_kernel<<<2048, 256, 0, stream>>>(tp[1], t_ipw, (long)IPW);
  cvt_kernel<<<2048, 256, 0, stream>>>(tp[3], t_ow, (long)OW);
  cvt_kernel<<<2048, 256, 0, stream>>>(tp[7], t_f1w, (long)F1W);
  cvt_kernel<<<2048, 256, 0, stream>>>(tp[9], t_f2w, (long)F2W);
  cvt_kernel<<<2048, 256, 0, stream>>>(up[1], u_ipw, (long)IPW);
  cvt_kernel<<<2048, 256, 0, stream>>>(up[3], u_ow, (long)OW);
  cvt_kernel<<<2048, 256, 0, stream>>>(up[7], u_f1w, (long)F1W);
  cvt_kernel<<<2048, 256, 0, stream>>>(up[9], u_f2w, (long)F2W);

  // text encoder
  EncW tw{ttok, TSEQ, tp[0], tp[2], tp[4], tp[5], tp[6], tp[8], tp[10], tp[11], tp[12],
          t_ipw, t_ow, t_f1w, t_f2w, TPAD};
  run_encoder(stream, tw, bb);
  rowsq_kernel<<<BATCH * TSEQ, 256, 0, stream>>>(bb.xf, tn);
  hipMemcpyAsync(tfh, bb.xh, (size_t)BATCH * TSEQ * D_MODEL * 2, hipMemcpyDeviceToDevice, stream);

  // unit encoder
  EncW uw{utok, USEQ, up[0], up[2], up[4], up[5], up[6], up[8], up[10], up[11], up[12],
          u_ipw, u_ow, u_f1w, u_f2w, UPAD};
  run_encoder(stream, uw, bb);
  rowsq_kernel<<<BATCH * USEQ, 256, 0, stream>>>(bb.xf, un);

  // cross[b] = uf[b] @ tf[b]^T  -> d_out, then in-place dist + log_softmax
  float* out = (float*)d_out;
  launch_gemm(stream, bb.xh, D_MODEL, (long)USEQ * D_MODEL, 0,
              tfh, D_MODEL, (long)TSEQ * D_MODEL, 0,
              out, nullptr, TSEQ, (long)USEQ * TSEQ, 0,
              nullptr, USEQ, TSEQ, D_MODEL, 1.0f, 0, 1, BATCH);
  dist_lsm_kernel<<<dim3(USEQ, BATCH), 256, 0, stream>>>(out, un, tn, utok, ttok);
}

// Round 2
// 2748.433 us; speedup vs baseline: 1.8395x; 1.8395x over previous
//
#include <hip/hip_runtime.h>
#include <stdint.h>

typedef _Float16 half_t;
typedef _Float16 half4 __attribute__((ext_vector_type(4)));
typedef _Float16 half8 __attribute__((ext_vector_type(8)));
typedef float floatx4 __attribute__((ext_vector_type(4)));

#define D_MODEL 1024
#define NHEAD 8
#define DHEAD 128
#define FF_DIM 2048
#define NLAYER 3
#define BATCH 8
#define TSEQ 256
#define USEQ 1024
#define TPAD 128256
#define UPAD 10000
#define TEMP_ 5e-4f
#define SCALE_QK 0.08838834764831845f

// ---------------- block reduction helpers (block = 256 = 4 waves) ----------------
__device__ inline float blk_sum(float v, float* sh) {
#pragma unroll
  for (int o = 32; o; o >>= 1) v += __shfl_xor(v, o, 64);
  __syncthreads();
  if ((threadIdx.x & 63) == 0) sh[threadIdx.x >> 6] = v;
  __syncthreads();
  return sh[0] + sh[1] + sh[2] + sh[3];
}
__device__ inline float blk_max(float v, float* sh) {
#pragma unroll
  for (int o = 32; o; o >>= 1) v = fmaxf(v, __shfl_xor(v, o, 64));
  __syncthreads();
  if ((threadIdx.x & 63) == 0) sh[threadIdx.x >> 6] = v;
  __syncthreads();
  return fmaxf(fmaxf(sh[0], sh[1]), fmaxf(sh[2], sh[3]));
}

// ---------------- async global->LDS staging (width 16) ----------------
typedef const __attribute__((address_space(1))) uint32_t* gas1_u32;
typedef __attribute__((address_space(3))) uint32_t* las3_u32;
__device__ __forceinline__ void gload16(const half_t* g, half_t* l) {
  __builtin_amdgcn_global_load_lds((gas1_u32)g, (las3_u32)l, 16, 0, 0);
}

// ---------------- generic batched GEMM: C = alpha * A[M,K] * B[N,K]^T + bias ----------------
// A,B fp16 K-contiguous. z -> (zb = z/zdiv, zh = z%zdiv) offsets. M,N mult of 128; K mult of 64.
// Staging via global_load_lds width-16: LDS dest linear (wave-uniform base + lane*16);
// the XOR swizzle (granule g of row r holds source granule g^(r&7)) is applied on the
// GLOBAL source address, reads use the same XOR -> conflict-free ds_read_b128 (rule #21).
__global__ __launch_bounds__(256)
void gemm_bt_kernel(const half_t* __restrict__ A, long lda, long sAb, long sAz,
                    const half_t* __restrict__ B, long ldb, long sBb, long sBz,
                    float* __restrict__ Cf, half_t* __restrict__ Ch,
                    long ldc, long sCb, long sCz,
                    const float* __restrict__ bias,
                    int M, int N, int K, float alpha, int relu, int zdiv) {
  __shared__ __align__(16) half_t As[128 * 64];
  __shared__ __align__(16) half_t Bs[128 * 64];

  const int z = blockIdx.z;
  const int zb = z / zdiv, zh = z % zdiv;
  A += (long)zb * sAb + (long)zh * sAz;
  B += (long)zb * sBb + (long)zh * sBz;
  const long coff = (long)zb * sCb + (long)zh * sCz;

  const int tid = threadIdx.x;
  const int lane = tid & 63;
  const int wid = tid >> 6;
  const long row0 = (long)blockIdx.y * 128;
  const long col0 = (long)blockIdx.x * 128;

  // staging geometry: wave wid, iteration i covers rows [i*32 + wid*8, +8), 64 halves each.
  const int srw = lane >> 3;     // row within 8-row block
  const int sg = lane & 7;       // LDS granule (linear dest)

  const int wm = (wid & 1) << 6;
  const int wn = (wid >> 1) << 6;
  const int fm = lane & 15;
  const int quad = lane >> 4;

  floatx4 acc[4][4] = {};

  for (int k0 = 0; k0 < K; k0 += 64) {
#pragma unroll
    for (int i = 0; i < 4; ++i) {
      const int rb = (i << 5) + (wid << 3);   // wave-uniform row-block base
      const int rr = rb + srw;                // this lane's row
      const int gg = sg ^ (rr & 7);           // pre-swizzled source granule
      gload16(A + (row0 + rr) * lda + k0 + (gg << 3), &As[rb << 6]);
      gload16(B + (col0 + rr) * ldb + k0 + (gg << 3), &Bs[rb << 6]);
    }
    __syncthreads();
#pragma unroll
    for (int kk = 0; kk < 64; kk += 32) {
      const int gq = (kk >> 3) + quad;  // granule for this quad
      half8 af[4], bfr[4];
#pragma unroll
      for (int mi = 0; mi < 4; ++mi) {
        const int r = wm + (mi << 4) + fm;
        af[mi] = *(const half8*)(&As[(r << 6) + ((gq ^ (r & 7)) << 3)]);
      }
#pragma unroll
      for (int ni = 0; ni < 4; ++ni) {
        const int r = wn + (ni << 4) + fm;
        bfr[ni] = *(const half8*)(&Bs[(r << 6) + ((gq ^ (r & 7)) << 3)]);
      }
#pragma unroll
      for (int mi = 0; mi < 4; ++mi)
#pragma unroll
        for (int ni = 0; ni < 4; ++ni)
          acc[mi][ni] = __builtin_amdgcn_mfma_f32_16x16x32_f16(af[mi], bfr[ni], acc[mi][ni], 0, 0, 0);
    }
    __syncthreads();
  }

  // epilogue: C/D layout col = lane&15, row = quad*4 + r (m89/m91-verified)
#pragma unroll
  for (int ni = 0; ni < 4; ++ni) {
    const long col = col0 + wn + (ni << 4) + fm;
    const float bv = bias ? bias[col] : 0.0f;
#pragma unroll
    for (int mi = 0; mi < 4; ++mi) {
#pragma unroll
      for (int r = 0; r < 4; ++r) {
        const long row = row0 + wm + (mi << 4) + (quad << 2) + r;
        float v = acc[mi][ni][r] * alpha + bv;
        if (relu) v = fmaxf(v, 0.0f);
        const long idx = coff + row * ldc + col;
        if (Cf) Cf[idx] = v;
        if (Ch) Ch[idx] = (half_t)v;
      }
    }
  }
}

// ---------------- elementwise / small kernels (vectorized, G13) ----------------
__global__ void cvt_kernel(const float* __restrict__ in, half_t* __restrict__ out, long n) {
  const long n4 = n >> 2;
  long i = (long)blockIdx.x * 256 + threadIdx.x;
  const long stride = (long)gridDim.x * 256;
  for (; i < n4; i += stride) {
    const float4 v = *(const float4*)(in + (i << 2));
    half4 h;
    h[0] = (half_t)v.x; h[1] = (half_t)v.y; h[2] = (half_t)v.z; h[3] = (half_t)v.w;
    *(half4*)(out + (i << 2)) = h;
  }
}

__global__ __launch_bounds__(256) void embed_kernel(const int* __restrict__ tok,
                                                    const float* __restrict__ emb,
                                                    float* __restrict__ xf, half_t* __restrict__ xh) {
  const long r = blockIdx.x;
  const long src = (long)tok[r] * D_MODEL;
  const int j = threadIdx.x << 2;  // 256 threads x 4 floats = 1024
  const float4 v = *(const float4*)(emb + src + j);
  *(float4*)(xf + r * D_MODEL + j) = v;
  half4 h;
  h[0] = (half_t)v.x; h[1] = (half_t)v.y; h[2] = (half_t)v.z; h[3] = (half_t)v.w;
  *(half4*)(xh + r * D_MODEL + j) = h;
}

// x = LN(x + y) * s + b  (in-place on xf, also emits fp16 copy)
__global__ __launch_bounds__(256) void ln_kernel(float* x, const float* y,
                                                 const float* s, const float* b, half_t* xh) {
  const int row = blockIdx.x, tid = threadIdx.x;
  const int j0 = tid << 2;
  float* xr = x + (long)row * D_MODEL;
  const float* yr = y + (long)row * D_MODEL;
  const float4 xv = *(const float4*)(xr + j0);
  const float4 yv = *(const float4*)(yr + j0);
  float v[4] = {xv.x + yv.x, xv.y + yv.y, xv.z + yv.z, xv.w + yv.w};
  float sum = v[0] + v[1] + v[2] + v[3];
  float sq = v[0] * v[0] + v[1] * v[1] + v[2] * v[2] + v[3] * v[3];
  __shared__ float sh[4];
  sum = blk_sum(sum, sh);
  sq = blk_sum(sq, sh);
  const float mean = sum * (1.0f / D_MODEL);
  const float var = sq * (1.0f / D_MODEL) - mean * mean;
  const float inv = rsqrtf(var + 1e-5f);
  const float4 sv = *(const float4*)(s + j0);
  const float4 bv = *(const float4*)(b + j0);
  float4 ov;
  ov.x = (v[0] - mean) * inv * sv.x + bv.x;
  ov.y = (v[1] - mean) * inv * sv.y + bv.y;
  ov.z = (v[2] - mean) * inv * sv.z + bv.z;
  ov.w = (v[3] - mean) * inv * sv.w + bv.w;
  *(float4*)(xr + j0) = ov;
  half4 h;
  h[0] = (half_t)ov.x; h[1] = (half_t)ov.y; h[2] = (half_t)ov.z; h[3] = (half_t)ov.w;
  *(half4*)(xh + (long)row * D_MODEL + j0) = h;
}

// in-place masked softmax over rows of sc[z][q][S]
__global__ __launch_bounds__(256) void softmax_kernel(half_t* sc, const int* __restrict__ tok,
                                                      int S, int padidx) {
  const int q = blockIdx.x, z = blockIdx.y;
  const int b = z >> 3;  // NHEAD == 8
  half_t* row = sc + (long)z * S * S + (long)q * S;
  const int* tb = tok + (long)b * S;
  const int tid = threadIdx.x;
  __shared__ float sh[4];
  if (S == 1024) {
    // vectorized: 4 contiguous elements per thread (half4 + int4 loads)
    const int j0 = tid << 2;
    const half4 h = *(const half4*)(row + j0);
    const int4 tk = *(const int4*)(tb + j0);
    float v[4];
    v[0] = (tk.x == padidx) ? -1e9f : (float)h[0];
    v[1] = (tk.y == padidx) ? -1e9f : (float)h[1];
    v[2] = (tk.z == padidx) ? -1e9f : (float)h[2];
    v[3] = (tk.w == padidx) ? -1e9f : (float)h[3];
    float m = fmaxf(fmaxf(v[0], v[1]), fmaxf(v[2], v[3]));
    m = blk_max(m, sh);
    float ssum = 0.f;
#pragma unroll
    for (int c = 0; c < 4; ++c) { v[c] = expf(v[c] - m); ssum += v[c]; }
    ssum = blk_sum(ssum, sh);
    const float inv = 1.0f / ssum;
    half4 o;
#pragma unroll
    for (int c = 0; c < 4; ++c) o[c] = (half_t)(v[c] * inv);
    *(half4*)(row + j0) = o;
  } else {
    // S == 256: one element per thread
    float x = (float)row[tid];
    if (tb[tid] == padidx) x = -1e9f;
    const float m = blk_max(x, sh);
    const float e = expf(x - m);
    const float ssum = blk_sum(e, sh);
    row[tid] = (half_t)(e / ssum);
  }
}

// repack V section of qkv into vt[b*H+h][DHEAD][S] (transposed, for gemm_bt PV)
__global__ __launch_bounds__(256) void vtrans_kernel(const half_t* __restrict__ qkv,
                                                     half_t* __restrict__ vt, int S) {
  __shared__ half_t tile[64][65];
  const int s0 = blockIdx.x * 64, d0 = blockIdx.y * 64, z = blockIdx.z;
  const int b = z >> 3, h = z & 7;
  const half_t* src = qkv + (long)b * S * (3 * D_MODEL) + 2 * D_MODEL + h * DHEAD;
  for (int idx = threadIdx.x; idx < 4096; idx += 256) {
    const int r = idx >> 6, c = idx & 63;
    tile[r][c] = src[(long)(s0 + r) * (3 * D_MODEL) + d0 + c];
  }
  __syncthreads();
  half_t* dst = vt + ((long)z * DHEAD + d0) * S + s0;
  for (int idx = threadIdx.x; idx < 4096; idx += 256) {
    const int r = idx >> 6, c = idx & 63;
    dst[(long)r * S + c] = tile[c][r];
  }
}

__global__ __launch_bounds__(256) void rowsq_kernel(const float* __restrict__ x, float* __restrict__ o) {
  const int row = blockIdx.x, tid = threadIdx.x;
  const float* xr = x + (long)row * D_MODEL;
  const float4 v = *(const float4*)(xr + (tid << 2));
  float s = v.x * v.x + v.y * v.y + v.z * v.z + v.w * v.w;
  __shared__ float sh[4];
  s = blk_sum(s, sh);
  if (tid == 0) o[row] = s;
}

// out row currently holds cross[b,u,:]; transform to log_softmax(-TEMP*(un+tn-2c)) with pad mask
__global__ __launch_bounds__(256) void dist_lsm_kernel(float* out, const float* __restrict__ un,
                                                       const float* __restrict__ tn,
                                                       const int* __restrict__ utok,
                                                       const int* __restrict__ ttok) {
  const int u = blockIdx.x, b = blockIdx.y, t = threadIdx.x;
  const long off = ((long)(b * USEQ + u)) * TSEQ;
  const float c = out[off + t];
  float x = -TEMP_ * (un[b * USEQ + u] + tn[b * TSEQ + t] - 2.0f * c);
  if (utok[b * USEQ + u] == UPAD || ttok[b * TSEQ + t] == TPAD) x = -1e9f;
  __shared__ float sh[4];
  const float m = blk_max(x, sh);
  const float e = expf(x - m);
  const float s = blk_sum(e, sh);
  out[off + t] = x - m - logf(s);
}

// ---------------- host-side orchestration ----------------
static void launch_gemm(hipStream_t st, const half_t* A, long lda, long sAb, long sAz,
                        const half_t* B, long ldb, long sBb, long sBz,
                        float* Cf, half_t* Ch, long ldc, long sCb, long sCz,
                        const float* bias, int M, int N, int K, float alpha, int relu,
                        int zdiv, int nz) {
  dim3 g(N / 128, M / 128, nz), blk(256);
  gemm_bt_kernel<<<g, blk, 0, st>>>(A, lda, sAb, sAz, B, ldb, sBb, sBz,
                                    Cf, Ch, ldc, sCb, sCz, bias, M, N, K, alpha, relu, zdiv);
}

struct EncW {
  const int* tok; int S;
  const float *emb, *ipb, *ob, *l1s, *l1b, *f1b, *f2b, *l2s, *l2b;
  const half_t *ipw, *ow, *f1w, *f2w;
  int padidx;
};
struct Bufs {
  float *xf, *yf;
  half_t *xh, *qkv, *vt, *sc, *oh, *ffh;
};

static void run_encoder(hipStream_t st, const EncW& w, const Bufs& bb) {
  const int S = w.S, Ntok = BATCH * S;
  embed_kernel<<<Ntok, 256, 0, st>>>(w.tok, w.emb, bb.xf, bb.xh);
  for (int l = 0; l < NLAYER; ++l) {
    // QKV projection -> qkv[Ntok, 3D] fp16
    launch_gemm(st, bb.xh, D_MODEL, 0, 0,
                w.ipw + (size_t)l * 3 * D_MODEL * D_MODEL, D_MODEL, 0, 0,
                nullptr, bb.qkv, 3 * D_MODEL, 0, 0,
                w.ipb + (size_t)l * 3 * D_MODEL, Ntok, 3 * D_MODEL, D_MODEL, 1.0f, 0, 1, 1);
    // V transpose repack
    vtrans_kernel<<<dim3(S / 64, DHEAD / 64, BATCH * NHEAD), 256, 0, st>>>(bb.qkv, bb.vt, S);
    // scores = scale * Q K^T   (per z = b*H + h, strided into qkv)
    launch_gemm(st, bb.qkv, 3 * D_MODEL, (long)S * 3 * D_MODEL, DHEAD,
                bb.qkv + D_MODEL, 3 * D_MODEL, (long)S * 3 * D_MODEL, DHEAD,
                nullptr, bb.sc, S, (long)NHEAD * S * S, (long)S * S,
                nullptr, S, S, DHEAD, SCALE_QK, 0, NHEAD, BATCH * NHEAD);
    softmax_kernel<<<dim3(S, BATCH * NHEAD), 256, 0, st>>>(bb.sc, w.tok, S, w.padidx);
    // O_head = P V  -> oh[Ntok, D] (heads concatenated)
    launch_gemm(st, bb.sc, S, (long)NHEAD * S * S, (long)S * S,
                bb.vt, S, (long)NHEAD * DHEAD * S, (long)DHEAD * S,
                nullptr, bb.oh, D_MODEL, (long)S * D_MODEL, DHEAD,
                nullptr, S, DHEAD, S, 1.0f, 0, NHEAD, BATCH * NHEAD);
    // output projection -> yf fp32
    launch_gemm(st, bb.oh, D_MODEL, 0, 0,
                w.ow + (size_t)l * D_MODEL * D_MODEL, D_MODEL, 0, 0,
                bb.yf, nullptr, D_MODEL, 0, 0,
                w.ob + (size_t)l * D_MODEL, Ntok, D_MODEL, D_MODEL, 1.0f, 0, 1, 1);
    ln_kernel<<<Ntok, 256, 0, st>>>(bb.xf, bb.yf, w.l1s + (size_t)l * D_MODEL,
                                    w.l1b + (size_t)l * D_MODEL, bb.xh);
    // FF1 (+ReLU) -> ffh fp16
    launch_gemm(st, bb.xh, D_MODEL, 0, 0,
                w.f1w + (size_t)l * FF_DIM * D_MODEL, D_MODEL, 0, 0,
                nullptr, bb.ffh, FF_DIM, 0, 0,
                w.f1b + (size_t)l * FF_DIM, Ntok, FF_DIM, D_MODEL, 1.0f, 1, 1, 1);
    // FF2 -> yf fp32
    launch_gemm(st, bb.ffh, FF_DIM, 0, 0,
                w.f2w + (size_t)l * D_MODEL * FF_DIM, FF_DIM, 0, 0,
                bb.yf, nullptr, D_MODEL, 0, 0,
                w.f2b + (size_t)l * D_MODEL, Ntok, D_MODEL, FF_DIM, 1.0f, 0, 1, 1);
    ln_kernel<<<Ntok, 256, 0, st>>>(bb.xf, bb.yf, w.l2s + (size_t)l * D_MODEL,
                                    w.l2b + (size_t)l * D_MODEL, bb.xh);
  }
}

extern "C" void kernel_launch(void* const* d_in, const int* in_sizes, int n_in,
                              void* d_out, int out_size, void* d_ws, size_t ws_size,
                              hipStream_t stream) {
  (void)in_sizes; (void)n_in; (void)out_size; (void)ws_size;
  const int* ttok = (const int*)d_in[0];
  const int* utok = (const int*)d_in[1];
  const float* tp[13];
  const float* up[13];
  for (int i = 0; i < 13; ++i) tp[i] = (const float*)d_in[2 + i];
  for (int i = 0; i < 13; ++i) up[i] = (const float*)d_in[15 + i];
  // index: 0 emb, 1 ipw, 2 ipb, 3 ow, 4 ob, 5 l1s, 6 l1b, 7 f1w, 8 f1b, 9 f2w, 10 f2b, 11 l2s, 12 l2b

  char* wp = (char*)d_ws;
  auto alloc = [&](size_t bytes) {
    void* p = wp;
    wp += (bytes + 255) & ~(size_t)255;
    return p;
  };
  const size_t IPW = (size_t)NLAYER * 3 * D_MODEL * D_MODEL;
  const size_t OW = (size_t)NLAYER * D_MODEL * D_MODEL;
  const size_t F1W = (size_t)NLAYER * FF_DIM * D_MODEL;
  const size_t F2W = (size_t)NLAYER * D_MODEL * FF_DIM;
  half_t* t_ipw = (half_t*)alloc(IPW * 2);
  half_t* t_ow = (half_t*)alloc(OW * 2);
  half_t* t_f1w = (half_t*)alloc(F1W * 2);
  half_t* t_f2w = (half_t*)alloc(F2W * 2);
  half_t* u_ipw = (half_t*)alloc(IPW * 2);
  half_t* u_ow = (half_t*)alloc(OW * 2);
  half_t* u_f1w = (half_t*)alloc(F1W * 2);
  half_t* u_f2w = (half_t*)alloc(F2W * 2);
  Bufs bb;
  bb.xf = (float*)alloc((size_t)BATCH * USEQ * D_MODEL * 4);
  bb.yf = (float*)alloc((size_t)BATCH * USEQ * D_MODEL * 4);
  bb.xh = (half_t*)alloc((size_t)BATCH * USEQ * D_MODEL * 2);
  bb.qkv = (half_t*)alloc((size_t)BATCH * USEQ * 3 * D_MODEL * 2);
  bb.vt = (half_t*)alloc((size_t)BATCH * NHEAD * DHEAD * USEQ * 2);
  bb.sc = (half_t*)alloc((size_t)BATCH * NHEAD * USEQ * USEQ * 2);
  bb.oh = (half_t*)alloc((size_t)BATCH * USEQ * D_MODEL * 2);
  bb.ffh = (half_t*)alloc((size_t)BATCH * USEQ * FF_DIM * 2);
  half_t* tfh = (half_t*)alloc((size_t)BATCH * TSEQ * D_MODEL * 2);
  float* tn = (float*)alloc((size_t)BATCH * TSEQ * 4);
  float* un = (float*)alloc((size_t)BATCH * USEQ * 4);

  // weight fp32 -> fp16
  cvt_kernel<<<1024, 256, 0, stream>>>(tp[1], t_ipw, (long)IPW);
  cvt_kernel<<<1024, 256, 0, stream>>>(tp[3], t_ow, (long)OW);
  cvt_kernel<<<1024, 256, 0, stream>>>(tp[7], t_f1w, (long)F1W);
  cvt_kernel<<<1024, 256, 0, stream>>>(tp[9], t_f2w, (long)F2W);
  cvt_kernel<<<1024, 256, 0, stream>>>(up[1], u_ipw, (long)IPW);
  cvt_kernel<<<1024, 256, 0, stream>>>(up[3], u_ow, (long)OW);
  cvt_kernel<<<1024, 256, 0, stream>>>(up[7], u_f1w, (long)F1W);
  cvt_kernel<<<1024, 256, 0, stream>>>(up[9], u_f2w, (long)F2W);

  // text encoder
  EncW tw{ttok, TSEQ, tp[0], tp[2], tp[4], tp[5], tp[6], tp[8], tp[10], tp[11], tp[12],
          t_ipw, t_ow, t_f1w, t_f2w, TPAD};
  run_encoder(stream, tw, bb);
  rowsq_kernel<<<BATCH * TSEQ, 256, 0, stream>>>(bb.xf, tn);
  hipMemcpyAsync(tfh, bb.xh, (size_t)BATCH * TSEQ * D_MODEL * 2, hipMemcpyDeviceToDevice, stream);

  // unit encoder
  EncW uw{utok, USEQ, up[0], up[2], up[4], up[5], up[6], up[8], up[10], up[11], up[12],
          u_ipw, u_ow, u_f1w, u_f2w, UPAD};
  run_encoder(stream, uw, bb);
  rowsq_kernel<<<BATCH * USEQ, 256, 0, stream>>>(bb.xf, un);

  // cross[b] = uf[b] @ tf[b]^T  -> d_out, then in-place dist + log_softmax
  float* out = (float*)d_out;
  launch_gemm(stream, bb.xh, D_MODEL, (long)USEQ * D_MODEL, 0,
              tfh, D_MODEL, (long)TSEQ * D_MODEL, 0,
              out, nullptr, TSEQ, (long)USEQ * TSEQ, 0,
              nullptr, USEQ, TSEQ, D_MODEL, 1.0f, 0, 1, BATCH);
  dist_lsm_kernel<<<dim3(USEQ, BATCH), 256, 0, stream>>>(out, un, tn, utok, ttok);
}